// Round 15
// baseline (208.299 us; speedup 1.0000x reference)
//
#include <hip/hip_runtime.h>
#include <math.h>

// Shapes: B=32, L=128, H=768, E=64, H+E=832, 2H=1536
#define NB 32
#define NL 128
#define NH 768
#define NE 64

// ---------------- ws layout (bytes) ----------------
#define OFF_ASLOT   32784     // int[32*128]                        -> 49168
#define OFF_AIDX    49168     // int[32*4]                          -> 49680
#define OFF_NASP    49680     // int[32]                            -> 49808
#define OFF_AJCNT   49808     // int[32*4]                          -> 50320
#define OFF_AJIDX   50320     // int[32*4*128]                      -> 115856
#define OFF_RMAP    148624    // int[128]                           -> 149136
#define OFF_BZD     155280    // float[2]                           -> 155296
#define OFF_YB      155296    // float[128*768]                     -> 548512
#define OFF_DG      548512    // float[128*64]                      -> 581280
#define OFF_ZSAP    2154144   // float[4*128*768] zsa partials      -> 3727008
#define OFF_VIP     6872736   // float[8*768]                       -> 6897312
#define OFF_VJP     6897312   // float[8*768]                       -> 6921888
#define OFF_WT      6921888   // float[768*768]  Wt = Wfy@Wz        -> 9281184
#define OFF_WE      9281184   // float[768*768]  We = Wh_n@Wt       -> 11640480
#define OFF_WDT     11640480  // float[4*64*768] Wd^T partials      -> 12427296
#define OFF_UP      12427296  // float[4*768]    u partials         -> 12439584
#define OFF_C1      12439584  // float[768]      c1 = Wh_n@u        -> 12442656

// ======== KA (stage 1): masks(0-31) viP/vjP(32-55) bzd(56) uP(57-68)
//          Wt=Wfy@Wz(69-356) WdT=(Wh_n@WfD)^T partials(357-548) copy(549-4644) ========
__global__ __launch_bounds__(256) void kA(
    const int* __restrict__ adj, const int* __restrict__ asp_s, const int* __restrict__ asp_e,
    const float* __restrict__ Wz, const float* __restrict__ wa, const float* __restrict__ bz,
    const float* __restrict__ bert, const float* __restrict__ Wf, const float* __restrict__ Wh,
    int* __restrict__ aspect_slot, int* __restrict__ aspect_idx, int* __restrict__ nasp,
    int* __restrict__ aj_cnt, int* __restrict__ aj_idx, int* __restrict__ row_map,
    float* __restrict__ viP, float* __restrict__ vjP, float* __restrict__ bzd,
    float* __restrict__ uP, float* __restrict__ Wt, float* __restrict__ Wdtp,
    float* __restrict__ out) {
  int blk = blockIdx.x, tid = threadIdx.x;
  if (blk < 32) {
    int b = blk;
    __shared__ int asp_flag[128];
    __shared__ int s_aidx[4];
    __shared__ int s_nasp;
    if (tid < 128) {
      const int* arow = adj + ((size_t)(b * 128 + tid)) * 128;
      int any = 0;
      for (int j = 0; j < 128; j += 4) {
        int4 v = *(const int4*)(arow + j);
        any |= v.x | v.y | v.z | v.w;
      }
      int s0 = asp_s[b], e0 = asp_e[b];
      asp_flag[tid] = (tid >= s0 && tid <= e0 && any > 0) ? 1 : 0;
      aspect_slot[b * 128 + tid] = -1;
    }
    if (tid >= 128 && tid < 132) row_map[b * 4 + (tid - 128)] = b * 128;
    __syncthreads();
    if (tid == 0) {
      int n = 0;
      for (int i = 0; i < 128; ++i)
        if (asp_flag[i] && n < 4) s_aidx[n++] = i;
      s_nasp = n;
      nasp[b] = n;
    }
    __syncthreads();
    int w = tid >> 6, l = tid & 63;
    if (w < s_nasp) {
      int a = s_aidx[w];
      if (l == 0) {
        aspect_idx[b * 4 + w] = a;
        aspect_slot[b * 128 + a] = w;
        row_map[b * 4 + w] = b * 128 + a;
      }
      const int* ar = adj + ((size_t)(b * 128 + a)) * 128;
      int v0 = (ar[l] > 0) ? 1 : 0;
      int v1 = (ar[l + 64] > 0) ? 1 : 0;
      unsigned long long m0 = __ballot(v0);
      unsigned long long m1 = __ballot(v1);
      unsigned long long below = (1ull << l) - 1ull;
      int c0 = __popcll(m0 & below);
      int c1x = __popcll(m0) + __popcll(m1 & below);
      int* dst = aj_idx + (size_t)(b * 4 + w) * 128;
      if (v0) dst[c0] = l;
      if (v1) dst[c1x] = l + 64;
      if (l == 0) aj_cnt[b * 4 + w] = __popcll(m0) + __popcll(m1);
    }
  } else if (blk < 56) {
    int idx = blk - 32;
    int kb = idx % 3, hb = idx / 3;
    int k = kb * 256 + tid;
    int h0 = hb * 96;
    float ai = 0.f, aj = 0.f;
#pragma unroll 8
    for (int h = h0; h < h0 + 96; ++h) {
      float w = Wz[(size_t)h * 768 + k];
      ai += w * wa[h];
      aj += w * wa[768 + h];
    }
    viP[hb * 768 + k] = ai;
    vjP[hb * 768 + k] = aj;
  } else if (blk == 56) {
    if (tid < 64) {
      float bi = 0.f, bj = 0.f;
#pragma unroll
      for (int q = 0; q < 12; ++q) {
        float bv = bz[q * 64 + tid];
        bi += bv * wa[q * 64 + tid];
        bj += bv * wa[768 + q * 64 + tid];
      }
#pragma unroll
      for (int d = 32; d; d >>= 1) { bi += __shfl_xor(bi, d, 64); bj += __shfl_xor(bj, d, 64); }
      if (tid == 0) { bzd[0] = bi; bzd[1] = bj; }
    }
  } else if (blk < 69) {
    // ---- uP = Wfy @ bz partials (12: 3 hc x 4 kc) ----
    int idx = blk - 57;
    int hc = idx >> 2, kc = idx & 3;
    int hh = hc * 256 + tid;
    const float4* wp = (const float4*)(Wf + (size_t)hh * 832 + kc * 192);
    const float4* bp = (const float4*)(bz + kc * 192);
    float acc = 0.f;
#pragma unroll 4
    for (int k4 = 0; k4 < 48; ++k4) {
      float4 w = wp[k4];
      float4 b4 = bp[k4];
      acc += w.x * b4.x + w.y * b4.y + w.z * b4.z + w.w * b4.w;
    }
    uP[kc * 768 + hh] = acc;
  } else if (blk < 357) {
    // ---- Wt[m][k] = sum_h Wfy[m][h] Wz[h][k]  (288: 96 mg x 3 nc, 8 rows/block) ----
    __shared__ float Xs8[8][768];
    int idx = blk - 69;
    int mg = idx / 3, nc = idx % 3;
    int m0 = mg * 8;
    for (int q = tid; q < 8 * 768; q += 256) {
      int r = q / 768, c = q - r * 768;
      Xs8[r][c] = Wf[(size_t)(m0 + r) * 832 + c];
    }
    __syncthreads();
    int kg = tid & 63, wv = tid >> 6;
    int mA = wv * 2, mB = wv * 2 + 1;
    int n4 = nc * 256 + kg * 4;
    float4 a0 = make_float4(0.f, 0.f, 0.f, 0.f);
    float4 a1 = make_float4(0.f, 0.f, 0.f, 0.f);
#pragma unroll 4
    for (int h = 0; h < 768; ++h) {
      float4 wz = *(const float4*)(Wz + (size_t)h * 768 + n4);
      float x0 = Xs8[mA][h], x1 = Xs8[mB][h];
      a0.x += x0 * wz.x; a0.y += x0 * wz.y; a0.z += x0 * wz.z; a0.w += x0 * wz.w;
      a1.x += x1 * wz.x; a1.y += x1 * wz.y; a1.z += x1 * wz.z; a1.w += x1 * wz.w;
    }
    *(float4*)(Wt + (size_t)(m0 + mA) * 768 + n4) = a0;
    *(float4*)(Wt + (size_t)(m0 + mB) * 768 + n4) = a1;
  } else if (blk < 549) {
    // ---- WdT partials: Wd[m][e] = sum_h Wh_n[m][h] WfD[h][e]; store Wdtp[kc][e][m] ----
    __shared__ float XsW[16][192];
    int idx = blk - 357;
    int mgd = idx >> 2, kc = idx & 3;
    int m0 = mgd * 16;
    for (int q = tid; q < 16 * 192; q += 256) {
      int r = q / 192, c = q - r * 192;
      XsW[r][c] = Wh[(size_t)(m0 + r) * 1536 + kc * 192 + c];
    }
    __syncthreads();
    int e = tid & 63, mq = tid >> 6;
    float acc[4] = {};
    for (int h = 0; h < 192; ++h) {
      float wf = Wf[(size_t)(kc * 192 + h) * 832 + 768 + e];
#pragma unroll
      for (int j = 0; j < 4; ++j) acc[j] += XsW[mq * 4 + j][h] * wf;
    }
#pragma unroll
    for (int j = 0; j < 4; ++j)
      Wdtp[((size_t)kc * 64 + e) * 768 + m0 + mq * 4 + j] = acc[j];
  } else {
    // ---- copy one output row; zero it if it's an update row ----
    int row = blk - 549;  // 0..4095
    int b = row >> 7, i = row & 127;
    __shared__ int s_upd;
    if (tid == 0) s_upd = 0;
    __syncthreads();
    if (i > 0) {
      int ip = i - 1;
      int s0 = asp_s[b], e0 = asp_e[b];
      if (ip >= s0 && ip <= e0 && tid < 64) {
        const int2* ar = (const int2*)(adj + ((size_t)(b * 128 + ip)) * 128);
        int2 v = ar[tid];
        unsigned long long m = __ballot((v.x | v.y) != 0);
        if (tid == 0 && m != 0ull) s_upd = 1;
      }
    }
    __syncthreads();
    if (tid < 192) {
      float4 v = make_float4(0.f, 0.f, 0.f, 0.f);
      if (!s_upd) v = ((const float4*)bert)[(size_t)row * 192 + tid];
      ((float4*)out)[(size_t)row * 192 + tid] = v;
    }
  }
}

// ======== KB (stage 2): attn+sij(0-31) zsa partials(32-415) We=Wh_n@Wt(416-703) c1(704) ========
__global__ __launch_bounds__(256) void kB(
    const float* __restrict__ dep, const float* __restrict__ bert,
    const float* __restrict__ wa, const float* __restrict__ ba,
    const float* __restrict__ viP, const float* __restrict__ vjP, const float* __restrict__ bzd,
    const float* __restrict__ Wz, const float* __restrict__ bz, const float* __restrict__ Wh,
    const float* __restrict__ Wt, const float* __restrict__ uP,
    const int* __restrict__ nasp, const int* __restrict__ aspect_idx,
    const int* __restrict__ aj_cnt, const int* __restrict__ aj_idx,
    const int* __restrict__ row_map,
    float* __restrict__ YB, float* __restrict__ DG, float* __restrict__ zsap,
    float* __restrict__ We, float* __restrict__ c1) {
  int blk = blockIdx.x, tid = threadIdx.x;
  if (blk < 32) {
    int b = blk;
    int na = nasp[b];
    if (na == 0) return;
    __shared__ float vis[768];
    __shared__ float vjs[768];
    __shared__ float att[4][128];
    __shared__ float sjs[4][128];
    __shared__ float sis[4];
    __shared__ int jl[4][128];
    __shared__ int aidx[4];
    __shared__ int ajc[4];
    __shared__ float wae[64];
    if (tid < 4) { aidx[tid] = aspect_idx[b * 4 + tid]; ajc[tid] = aj_cnt[b * 4 + tid]; }
    if (tid < 64) wae[tid] = wa[1536 + tid];
    for (int q = tid; q < 512; q += 256) jl[q >> 7][q & 127] = aj_idx[b * 512 + q];
    for (int q = tid; q < 768; q += 256) {
      float a = 0.f, c = 0.f;
#pragma unroll
      for (int hb = 0; hb < 8; ++hb) { a += viP[hb * 768 + q]; c += vjP[hb * 768 + q]; }
      vis[q] = a;
      vjs[q] = c;
    }
    __syncthreads();
    int w = tid >> 6, l = tid & 63;
    float bzd0 = bzd[0], bzd1 = bzd[1];
    int offs[5];
    {
      int o = 0;
      for (int w2 = 0; w2 < 4; ++w2) { offs[w2] = o; if (w2 < na) o += 1 + ajc[w2]; }
      offs[4] = o;
    }
    for (int p = w; p < offs[4]; p += 4) {
      int w2 = 0;
      if (p >= offs[1]) w2 = 1;
      if (p >= offs[2]) w2 = 2;
      if (p >= offs[3]) w2 = 3;
      int idx = p - offs[w2];
      int row = (idx == 0) ? aidx[w2] : jl[w2][idx - 1];
      const float* br = bert + (size_t)(b * 128 + ((row + 1) & 127)) * 768;
      float acc = 0.f;
      if (idx == 0) {
#pragma unroll
        for (int q = 0; q < 12; ++q) acc += br[q * 64 + l] * vis[q * 64 + l];
      } else {
#pragma unroll
        for (int q = 0; q < 12; ++q) acc += br[q * 64 + l] * vjs[q * 64 + l];
      }
#pragma unroll
      for (int d = 32; d; d >>= 1) acc += __shfl_xor(acc, d, 64);
      if (l == 0) {
        if (idx == 0) sis[w2] = acc + bzd0;
        else sjs[w2][idx - 1] = acc + bzd1;
      }
    }
    __syncthreads();
    if (w >= na) return;
    int a = aidx[w], cj = ajc[w];
    float sib = sis[w] + ba[0];
    const float* depa = dep + ((size_t)(b * 128 + a)) * 128 * 64;
    float sc0 = -INFINITY, sc1 = -INFINITY;
    for (int t = l; t < cj; t += 64) {
      int j = jl[w][t];
      const float4* dp = (const float4*)(depa + (size_t)j * 64);
      float se = 0.f;
#pragma unroll
      for (int q = 0; q < 16; ++q) {
        float4 v = dp[q];
        se += v.x * wae[4 * q] + v.y * wae[4 * q + 1] + v.z * wae[4 * q + 2] + v.w * wae[4 * q + 3];
      }
      float sc = sib + sjs[w][t] + se;
      sc = (sc >= 0.f) ? sc : 0.01f * sc;
      if (t < 64) sc0 = sc; else sc1 = sc;
    }
    float mx = fmaxf(sc0, sc1);
#pragma unroll
    for (int d = 32; d; d >>= 1) mx = fmaxf(mx, __shfl_xor(mx, d, 64));
    float p0 = expf(sc0 - mx), p1 = expf(sc1 - mx);
    float sm = p0 + p1;
#pragma unroll
    for (int d = 32; d; d >>= 1) sm += __shfl_xor(sm, d, 64);
    float inv = 1.f / sm;
    if (l < cj) att[w][l] = p0 * inv;
    if (l + 64 < cj) att[w][l + 64] = p1 * inv;
    float y[12];
#pragma unroll
    for (int q = 0; q < 12; ++q) y[q] = 0.f;
    float dacc = 0.f;
    for (int t = 0; t < cj; ++t) {
      float at = att[w][t];
      int j = jl[w][t];
      const float* br = bert + (size_t)(b * 128 + ((j + 1) & 127)) * 768;
#pragma unroll
      for (int q = 0; q < 12; ++q) y[q] += at * br[q * 64 + l];
      dacc += at * depa[(size_t)j * 64 + l];
    }
    float* yr = YB + (size_t)(b * 4 + w) * 768;
#pragma unroll
    for (int q = 0; q < 12; ++q) yr[q * 64 + l] = y[q];
    DG[(b * 4 + w) * 64 + l] = dacc;
  } else if (blk < 416) {
    __shared__ float Xs[4][192];
    int idx = blk - 32;
    int kc = idx & 3, hc = (idx >> 2) % 3, bx = idx / 12;
    int s0 = bx * 4;
    if (tid < 192) {
      int r = tid / 48, c = tid - r * 48;
      int zrow = row_map[s0 + r];
      int bb = zrow >> 7, ii = zrow & 127;
      const float4* src = (const float4*)(bert + ((size_t)(bb * 128) + ((ii + 1) & 127)) * 768) + kc * 48;
      ((float4*)Xs[r])[c] = src[c];
    }
    __syncthreads();
    int h = hc * 256 + tid;
    const float4* wp = (const float4*)(Wz + (size_t)h * 768) + kc * 48;
    float accA[4] = {};
    float accB[4] = {};
#pragma unroll 6
    for (int k4 = 0; k4 < 24; ++k4) {
      float4 w0 = wp[k4];
      float4 w1 = wp[k4 + 24];
#pragma unroll
      for (int r = 0; r < 4; ++r) {
        float4 x0 = ((const float4*)Xs[r])[k4];
        float4 x1 = ((const float4*)Xs[r])[k4 + 24];
        accA[r] += x0.x * w0.x + x0.y * w0.y + x0.z * w0.z + x0.w * w0.w;
        accB[r] += x1.x * w1.x + x1.y * w1.y + x1.z * w1.z + x1.w * w1.w;
      }
    }
    float bzv = (kc == 0) ? bz[h] : 0.f;
#pragma unroll
    for (int r = 0; r < 4; ++r)
      zsap[((size_t)kc * 128 + s0 + r) * 768 + h] = accA[r] + accB[r] + bzv;
  } else if (blk < 704) {
    // ---- We[m][k] = sum_h Wh_n[m][h] Wt[h][k]  (288: 96 mg x 3 nc, 8 rows/block) ----
    __shared__ float Xs8[8][768];
    int idx = blk - 416;
    int mg = idx / 3, nc = idx % 3;
    int m0 = mg * 8;
    for (int q = tid; q < 8 * 768; q += 256) {
      int r = q / 768, c = q - r * 768;
      Xs8[r][c] = Wh[(size_t)(m0 + r) * 1536 + c];
    }
    __syncthreads();
    int kg = tid & 63, wv = tid >> 6;
    int mA = wv * 2, mB = wv * 2 + 1;
    int n4 = nc * 256 + kg * 4;
    float4 a0 = make_float4(0.f, 0.f, 0.f, 0.f);
    float4 a1 = make_float4(0.f, 0.f, 0.f, 0.f);
#pragma unroll 4
    for (int h = 0; h < 768; ++h) {
      float4 wt = *(const float4*)(Wt + (size_t)h * 768 + n4);
      float x0 = Xs8[mA][h], x1 = Xs8[mB][h];
      a0.x += x0 * wt.x; a0.y += x0 * wt.y; a0.z += x0 * wt.z; a0.w += x0 * wt.w;
      a1.x += x1 * wt.x; a1.y += x1 * wt.y; a1.z += x1 * wt.z; a1.w += x1 * wt.w;
    }
    *(float4*)(We + (size_t)(m0 + mA) * 768 + n4) = a0;
    *(float4*)(We + (size_t)(m0 + mB) * 768 + n4) = a1;
  } else {
    // ---- c1 = Wh_n @ u, u = sum uP ----
    __shared__ float us[768];
    for (int q = tid; q < 768; q += 256)
      us[q] = uP[q] + uP[768 + q] + uP[1536 + q] + uP[2304 + q];
    __syncthreads();
    for (int hh = tid; hh < 768; hh += 256) {
      const float4* wp = (const float4*)(Wh + (size_t)hh * 1536);
      float acc = 0.f;
#pragma unroll 4
      for (int k4 = 0; k4 < 192; ++k4) {
        float4 w = wp[k4];
        float4 u4 = *(const float4*)(us + k4 * 4);
        acc += w.x * u4.x + w.y * u4.y + w.z * u4.z + w.w * u4.w;
      }
      c1[hh] = acc;
    }
  }
}

// ======== KC (stage 3): zsa@Wh_z->out(0-383)  yb@We^T+c1->out(384-767)  D@Wd^T->out(768-863) ========
__global__ __launch_bounds__(256) void kC(
    const float* __restrict__ YB, const float* __restrict__ DG, const float* __restrict__ zsap,
    const float* __restrict__ Wh, const float* __restrict__ We, const float* __restrict__ Wdtp,
    const float* __restrict__ c1,
    const int* __restrict__ row_map, const int* __restrict__ nasp,
    float* __restrict__ out) {
  int blk = blockIdx.x, tid = threadIdx.x;
  __shared__ float Xs[4][192];
  if (blk < 384) {
    // ---- zsa half of temp: K-split 4, atomicAdd into out (verbatim R14) ----
    int idx = blk;
    int kc2 = idx & 3, nc = (idx >> 2) % 3, g = idx / 12;
    if (tid < 192) {
      int r = tid / 48, c = tid - r * 48;
      int row = g * 4 + r;
      int Q = kc2 * 48 + c;
      float4 p0 = *((const float4*)(zsap + (size_t)row * 768) + Q);
      float4 p1 = *((const float4*)(zsap + ((size_t)128 + row) * 768) + Q);
      float4 p2 = *((const float4*)(zsap + ((size_t)256 + row) * 768) + Q);
      float4 p3 = *((const float4*)(zsap + ((size_t)384 + row) * 768) + Q);
      ((float4*)Xs[r])[c] = make_float4(p0.x + p1.x + p2.x + p3.x, p0.y + p1.y + p2.y + p3.y,
                                        p0.z + p1.z + p2.z + p3.z, p0.w + p1.w + p2.w + p3.w);
    }
    __syncthreads();
    int h = nc * 256 + tid;
    float acc[4] = {};
    const float4* wp = (const float4*)(Wh + (size_t)h * 1536 + 768 + kc2 * 192);
#pragma unroll 4
    for (int k4 = 0; k4 < 48; ++k4) {
      float4 wv = wp[k4];
#pragma unroll
      for (int r = 0; r < 4; ++r) {
        float4 xv = ((const float4*)Xs[r])[k4];
        acc[r] += xv.x * wv.x + xv.y * wv.y + xv.z * wv.z + xv.w * wv.w;
      }
    }
#pragma unroll
    for (int r = 0; r < 4; ++r) {
      int row = g * 4 + r;
      int b = row >> 2, s = row & 3;
      if (s < nasp[b]) {
        int orow = row_map[row] + 1;
        atomicAdd(&out[(size_t)orow * 768 + h], acc[r]);
      }
    }
  } else if (blk < 768) {
    // ---- yb @ We^T + c1 -> out (K-split 4) ----
    int idx = blk - 384;
    int kc = idx & 3, nc = (idx >> 2) % 3, g = idx / 12;
    if (tid < 192) {
      int r = tid / 48, c = tid - r * 48;
      ((float4*)Xs[r])[c] = *((const float4*)(YB + (size_t)(g * 4 + r) * 768 + kc * 192) + c);
    }
    __syncthreads();
    int h = nc * 256 + tid;
    float acc[4] = {};
    const float4* wp = (const float4*)(We + (size_t)h * 768 + kc * 192);
#pragma unroll 4
    for (int k4 = 0; k4 < 48; ++k4) {
      float4 wv = wp[k4];
#pragma unroll
      for (int r = 0; r < 4; ++r) {
        float4 xv = ((const float4*)Xs[r])[k4];
        acc[r] += xv.x * wv.x + xv.y * wv.y + xv.z * wv.z + xv.w * wv.w;
      }
    }
    float cb = (kc == 0) ? c1[h] : 0.f;
#pragma unroll
    for (int r = 0; r < 4; ++r) {
      int row = g * 4 + r;
      int b = row >> 2, s = row & 3;
      if (s < nasp[b]) {
        int orow = row_map[row] + 1;
        atomicAdd(&out[(size_t)orow * 768 + h], acc[r] + cb);
      }
    }
  } else {
    // ---- D @ Wd^T -> out (K=64) ----
    int idx = blk - 768;
    int nc = idx % 3, g = idx / 3;
    if (tid < 64) {
#pragma unroll
      for (int r = 0; r < 4; ++r) Xs[r][tid] = DG[(size_t)(g * 4 + r) * 64 + tid];
    }
    __syncthreads();
    int h = nc * 256 + tid;
    float acc[4] = {};
    for (int e = 0; e < 64; ++e) {
      float wd = Wdtp[(size_t)e * 768 + h] + Wdtp[(size_t)(64 + e) * 768 + h] +
                 Wdtp[(size_t)(128 + e) * 768 + h] + Wdtp[(size_t)(192 + e) * 768 + h];
#pragma unroll
      for (int r = 0; r < 4; ++r) acc[r] += Xs[r][e] * wd;
    }
#pragma unroll
    for (int r = 0; r < 4; ++r) {
      int row = g * 4 + r;
      int b = row >> 2, s = row & 3;
      if (s < nasp[b]) {
        int orow = row_map[row] + 1;
        atomicAdd(&out[(size_t)orow * 768 + h], acc[r]);
      }
    }
  }
}

extern "C" void kernel_launch(void* const* d_in, const int* in_sizes, int n_in,
                              void* d_out, int out_size, void* d_ws, size_t ws_size,
                              hipStream_t stream) {
  const float* bert = (const float*)d_in[0];
  const float* dep  = (const float*)d_in[1];
  const int*   adj  = (const int*)d_in[2];
  const int*   asps = (const int*)d_in[3];
  const int*   aspe = (const int*)d_in[4];
  const float* Wz   = (const float*)d_in[5];
  const float* bz   = (const float*)d_in[6];
  const float* wa   = (const float*)d_in[7];
  const float* ba   = (const float*)d_in[8];
  const float* Wf   = (const float*)d_in[9];
  const float* Wh   = (const float*)d_in[10];
  float* out = (float*)d_out;
  char* ws = (char*)d_ws;

  int*   aspect_slot = (int*)(ws + OFF_ASLOT);
  int*   aspect_idx  = (int*)(ws + OFF_AIDX);
  int*   nasp        = (int*)(ws + OFF_NASP);
  int*   aj_cnt      = (int*)(ws + OFF_AJCNT);
  int*   aj_idx      = (int*)(ws + OFF_AJIDX);
  int*   row_map     = (int*)(ws + OFF_RMAP);
  float* bzd         = (float*)(ws + OFF_BZD);
  float* YB          = (float*)(ws + OFF_YB);
  float* DG          = (float*)(ws + OFF_DG);
  float* zsap        = (float*)(ws + OFF_ZSAP);
  float* viP         = (float*)(ws + OFF_VIP);
  float* vjP         = (float*)(ws + OFF_VJP);
  float* Wt          = (float*)(ws + OFF_WT);
  float* We          = (float*)(ws + OFF_WE);
  float* Wdtp        = (float*)(ws + OFF_WDT);
  float* uP          = (float*)(ws + OFF_UP);
  float* c1          = (float*)(ws + OFF_C1);

  kA<<<4645, 256, 0, stream>>>(adj, asps, aspe, Wz, wa, bz, bert, Wf, Wh,
                               aspect_slot, aspect_idx, nasp, aj_cnt, aj_idx, row_map,
                               viP, vjP, bzd, uP, Wt, Wdtp, out);
  kB<<<705, 256, 0, stream>>>(dep, bert, wa, ba, viP, vjP, bzd, Wz, bz, Wh, Wt, uP,
                              nasp, aspect_idx, aj_cnt, aj_idx, row_map,
                              YB, DG, zsap, We, c1);
  kC<<<864, 256, 0, stream>>>(YB, DG, zsap, Wh, We, Wdtp, c1, row_map, nasp, out);
}

// Round 16
// 86.765 us; speedup vs baseline: 2.4007x; 2.4007x over previous
//
#include <hip/hip_runtime.h>
#include <math.h>

// Shapes: B=32, L=128, H=768, E=64, H+E=832, 2H=1536
#define NB 32
#define NL 128
#define NH 768
#define NE 64

// ---------------- ws layout (bytes) ----------------
#define OFF_ASLOT   32784     // int[32*128] (written, unused now)  -> 49168
#define OFF_AIDX    49168     // int[32*4]                          -> 49680
#define OFF_NASP    49680     // int[32]                            -> 49808
#define OFF_AJCNT   49808     // int[32*4]                          -> 50320
#define OFF_AJIDX   50320     // int[32*4*128]                      -> 115856
#define OFF_RMAP    148624    // int[128]                           -> 149136
#define OFF_BZD     155280    // float[2]                           -> 155296
#define OFF_YB      155296    // float[128*768]                     -> 548512
#define OFF_DG      548512    // float[128*64]                      -> 581280
#define OFF_YP      581280    // float[4*128*768] y partials        -> 2154144
#define OFF_ZSAP    2154144   // float[4*128*768] zsa partials      -> 3727008
#define OFF_NBR     3727008   // float[128*768] nbr (full)          -> 4120224
#define OFF_VIP     6872736   // float[8*768] vi partials           -> 6897312
#define OFF_VJP     6897312   // float[8*768] vj partials           -> 6921888

// ---------------- KA (stage 1): masks+lists (0-31), vi/vj partials (32-55), bzd (56),
//                  copy/zero out rows (57-4152, one row per block) ----------------
__global__ __launch_bounds__(256) void kA(
    const int* __restrict__ adj, const int* __restrict__ asp_s, const int* __restrict__ asp_e,
    const float* __restrict__ Wz, const float* __restrict__ wa, const float* __restrict__ bz,
    const float* __restrict__ bert,
    int* __restrict__ aspect_slot, int* __restrict__ aspect_idx, int* __restrict__ nasp,
    int* __restrict__ aj_cnt, int* __restrict__ aj_idx, int* __restrict__ row_map,
    float* __restrict__ viP, float* __restrict__ vjP, float* __restrict__ bzd,
    float* __restrict__ out) {
  int blk = blockIdx.x, tid = threadIdx.x;
  if (blk < 32) {
    int b = blk;
    __shared__ int asp_flag[128];
    __shared__ int s_aidx[4];
    __shared__ int s_nasp;
    if (tid < 128) {
      const int* arow = adj + ((size_t)(b * 128 + tid)) * 128;
      int any = 0;
      for (int j = 0; j < 128; j += 4) {
        int4 v = *(const int4*)(arow + j);
        any |= v.x | v.y | v.z | v.w;
      }
      int s0 = asp_s[b], e0 = asp_e[b];
      asp_flag[tid] = (tid >= s0 && tid <= e0 && any > 0) ? 1 : 0;
      aspect_slot[b * 128 + tid] = -1;
    }
    if (tid >= 128 && tid < 132) row_map[b * 4 + (tid - 128)] = b * 128;
    __syncthreads();
    if (tid == 0) {
      int n = 0;
      for (int i = 0; i < 128; ++i)
        if (asp_flag[i] && n < 4) s_aidx[n++] = i;
      s_nasp = n;
      nasp[b] = n;
    }
    __syncthreads();
    int w = tid >> 6, l = tid & 63;
    if (w < s_nasp) {
      int a = s_aidx[w];
      if (l == 0) {
        aspect_idx[b * 4 + w] = a;
        aspect_slot[b * 128 + a] = w;
        row_map[b * 4 + w] = b * 128 + a;
      }
      const int* ar = adj + ((size_t)(b * 128 + a)) * 128;
      int v0 = (ar[l] > 0) ? 1 : 0;
      int v1 = (ar[l + 64] > 0) ? 1 : 0;
      unsigned long long m0 = __ballot(v0);
      unsigned long long m1 = __ballot(v1);
      unsigned long long below = (1ull << l) - 1ull;
      int c0 = __popcll(m0 & below);
      int c1 = __popcll(m0) + __popcll(m1 & below);
      int* dst = aj_idx + (size_t)(b * 4 + w) * 128;
      if (v0) dst[c0] = l;
      if (v1) dst[c1] = l + 64;
      if (l == 0) aj_cnt[b * 4 + w] = __popcll(m0) + __popcll(m1);
    }
  } else if (blk < 56) {
    int idx = blk - 32;
    int kb = idx % 3, hb = idx / 3;  // 3 k-chunks x 8 h-chunks
    int k = kb * 256 + tid;
    int h0 = hb * 96;
    float ai = 0.f, aj = 0.f;
#pragma unroll 8
    for (int h = h0; h < h0 + 96; ++h) {
      float w = Wz[(size_t)h * 768 + k];
      ai += w * wa[h];
      aj += w * wa[768 + h];
    }
    viP[hb * 768 + k] = ai;
    vjP[hb * 768 + k] = aj;
  } else if (blk == 56) {
    if (tid < 64) {
      float bi = 0.f, bj = 0.f;
#pragma unroll
      for (int q = 0; q < 12; ++q) {
        float bv = bz[q * 64 + tid];
        bi += bv * wa[q * 64 + tid];
        bj += bv * wa[768 + q * 64 + tid];
      }
#pragma unroll
      for (int d = 32; d; d >>= 1) { bi += __shfl_xor(bi, d, 64); bj += __shfl_xor(bj, d, 64); }
      if (tid == 0) { bzd[0] = bi; bzd[1] = bj; }
    }
  } else {
    // ---- copy one output row; zero it if it's an update row ----
    int row = blk - 57;  // 0..4095
    int b = row >> 7, i = row & 127;
    __shared__ int s_upd;
    if (tid == 0) s_upd = 0;
    __syncthreads();
    if (i > 0) {
      int ip = i - 1;
      int s0 = asp_s[b], e0 = asp_e[b];
      if (ip >= s0 && ip <= e0 && tid < 64) {
        const int2* ar = (const int2*)(adj + ((size_t)(b * 128 + ip)) * 128);
        int2 v = ar[tid];
        unsigned long long m = __ballot((v.x | v.y) != 0);
        if (tid == 0 && m != 0ull) s_upd = 1;
      }
    }
    __syncthreads();
    if (tid < 192) {
      float4 v = make_float4(0.f, 0.f, 0.f, 0.f);
      if (!s_upd) v = ((const float4*)bert)[(size_t)row * 192 + tid];
      ((float4*)out)[(size_t)row * 192 + tid] = v;
    }
  }
}

// ---------------- KB (stage 2): attn+sij (0-31), zsa partials (32-415) ----------------
__global__ __launch_bounds__(256) void kB(
    const float* __restrict__ dep, const float* __restrict__ bert,
    const float* __restrict__ wa, const float* __restrict__ ba,
    const float* __restrict__ viP, const float* __restrict__ vjP, const float* __restrict__ bzd,
    const float* __restrict__ Wz, const float* __restrict__ bz,
    const int* __restrict__ nasp, const int* __restrict__ aspect_idx,
    const int* __restrict__ aj_cnt, const int* __restrict__ aj_idx,
    const int* __restrict__ row_map,
    float* __restrict__ YB, float* __restrict__ DG, float* __restrict__ zsap) {
  int blk = blockIdx.x, tid = threadIdx.x;
  if (blk < 32) {
    int b = blk;
    int na = nasp[b];
    if (na == 0) return;
    __shared__ float vis[768];
    __shared__ float vjs[768];
    __shared__ float att[4][128];
    __shared__ float sjs[4][128];
    __shared__ float sis[4];
    __shared__ int jl[4][128];
    __shared__ int aidx[4];
    __shared__ int ajc[4];
    __shared__ float wae[64];
    if (tid < 4) { aidx[tid] = aspect_idx[b * 4 + tid]; ajc[tid] = aj_cnt[b * 4 + tid]; }
    if (tid < 64) wae[tid] = wa[1536 + tid];
    for (int q = tid; q < 512; q += 256) jl[q >> 7][q & 127] = aj_idx[b * 512 + q];
    for (int q = tid; q < 768; q += 256) {
      float a = 0.f, c = 0.f;
#pragma unroll
      for (int hb = 0; hb < 8; ++hb) { a += viP[hb * 768 + q]; c += vjP[hb * 768 + q]; }
      vis[q] = a;
      vjs[q] = c;
    }
    __syncthreads();
    int w = tid >> 6, l = tid & 63;
    float bzd0 = bzd[0], bzd1 = bzd[1];
    int offs[5];
    {
      int o = 0;
      for (int w2 = 0; w2 < 4; ++w2) { offs[w2] = o; if (w2 < na) o += 1 + ajc[w2]; }
      offs[4] = o;
    }
    for (int p = w; p < offs[4]; p += 4) {
      int w2 = 0;
      if (p >= offs[1]) w2 = 1;
      if (p >= offs[2]) w2 = 2;
      if (p >= offs[3]) w2 = 3;
      int idx = p - offs[w2];
      int row = (idx == 0) ? aidx[w2] : jl[w2][idx - 1];
      const float* br = bert + (size_t)(b * 128 + ((row + 1) & 127)) * 768;
      float acc = 0.f;
      if (idx == 0) {
#pragma unroll
        for (int q = 0; q < 12; ++q) acc += br[q * 64 + l] * vis[q * 64 + l];
      } else {
#pragma unroll
        for (int q = 0; q < 12; ++q) acc += br[q * 64 + l] * vjs[q * 64 + l];
      }
#pragma unroll
      for (int d = 32; d; d >>= 1) acc += __shfl_xor(acc, d, 64);
      if (l == 0) {
        if (idx == 0) sis[w2] = acc + bzd0;
        else sjs[w2][idx - 1] = acc + bzd1;
      }
    }
    __syncthreads();
    if (w >= na) return;
    int a = aidx[w], cj = ajc[w];
    float sib = sis[w] + ba[0];
    const float* depa = dep + ((size_t)(b * 128 + a)) * 128 * 64;
    float sc0 = -INFINITY, sc1 = -INFINITY;
    for (int t = l; t < cj; t += 64) {
      int j = jl[w][t];
      const float4* dp = (const float4*)(depa + (size_t)j * 64);
      float se = 0.f;
#pragma unroll
      for (int q = 0; q < 16; ++q) {
        float4 v = dp[q];
        se += v.x * wae[4 * q] + v.y * wae[4 * q + 1] + v.z * wae[4 * q + 2] + v.w * wae[4 * q + 3];
      }
      float sc = sib + sjs[w][t] + se;
      sc = (sc >= 0.f) ? sc : 0.01f * sc;
      if (t < 64) sc0 = sc; else sc1 = sc;
    }
    float mx = fmaxf(sc0, sc1);
#pragma unroll
    for (int d = 32; d; d >>= 1) mx = fmaxf(mx, __shfl_xor(mx, d, 64));
    float p0 = expf(sc0 - mx), p1 = expf(sc1 - mx);
    float sm = p0 + p1;
#pragma unroll
    for (int d = 32; d; d >>= 1) sm += __shfl_xor(sm, d, 64);
    float inv = 1.f / sm;
    if (l < cj) att[w][l] = p0 * inv;
    if (l + 64 < cj) att[w][l + 64] = p1 * inv;
    float y[12];
#pragma unroll
    for (int q = 0; q < 12; ++q) y[q] = 0.f;
    float dacc = 0.f;
    for (int t = 0; t < cj; ++t) {
      float at = att[w][t];
      int j = jl[w][t];
      const float* br = bert + (size_t)(b * 128 + ((j + 1) & 127)) * 768;
#pragma unroll
      for (int q = 0; q < 12; ++q) y[q] += at * br[q * 64 + l];
      dacc += at * depa[(size_t)j * 64 + l];
    }
    float* yr = YB + (size_t)(b * 4 + w) * 768;
#pragma unroll
    for (int q = 0; q < 12; ++q) yr[q * 64 + l] = y[q];
    DG[(b * 4 + w) * 64 + l] = dacc;
  } else {
    int idx = blk - 32;
    int kc = idx & 3, hc = (idx >> 2) % 3, bx = idx / 12;
    int s0 = bx * 4;
    __shared__ float Xs[4][192];
    if (tid < 192) {
      int r = tid / 48, c = tid - r * 48;
      int zrow = row_map[s0 + r];
      int bb = zrow >> 7, ii = zrow & 127;
      const float4* src = (const float4*)(bert + ((size_t)(bb * 128) + ((ii + 1) & 127)) * 768) + kc * 48;
      ((float4*)Xs[r])[c] = src[c];
    }
    __syncthreads();
    int h = hc * 256 + tid;
    const float4* wp = (const float4*)(Wz + (size_t)h * 768) + kc * 48;
    float accA[4] = {};
    float accB[4] = {};
#pragma unroll 6
    for (int k4 = 0; k4 < 24; ++k4) {
      float4 w0 = wp[k4];
      float4 w1 = wp[k4 + 24];
#pragma unroll
      for (int r = 0; r < 4; ++r) {
        float4 x0 = ((const float4*)Xs[r])[k4];
        float4 x1 = ((const float4*)Xs[r])[k4 + 24];
        accA[r] += x0.x * w0.x + x0.y * w0.y + x0.z * w0.z + x0.w * w0.w;
        accB[r] += x1.x * w1.x + x1.y * w1.y + x1.z * w1.z + x1.w * w1.w;
      }
    }
    float bzv = (kc == 0) ? bz[h] : 0.f;
#pragma unroll
    for (int r = 0; r < 4; ++r)
      zsap[((size_t)kc * 128 + s0 + r) * 768 + h] = accA[r] + accB[r] + bzv;
  }
}

// ---------------- KC (stage 3): g0 yp (0-383), zsa@Wh->out K4 (384-767), D@WfD->NBR (768-863) ----------------
__global__ __launch_bounds__(256) void kC(
    const float* __restrict__ YB, const float* __restrict__ DG, const float* __restrict__ zsap,
    const float* __restrict__ Wz, const float* __restrict__ bz,
    const float* __restrict__ Wf, const float* __restrict__ Wh,
    const int* __restrict__ row_map, const int* __restrict__ nasp,
    float* __restrict__ yp, float* __restrict__ NBR, float* __restrict__ out) {
  int blk = blockIdx.x, tid = threadIdx.x;
  __shared__ float Xs[4][192];
  if (blk < 384) {
    // ---- g0: yp = YB @ Wz^T + bz, K-split 4 ----
    int kc = blk & 3, hc = (blk >> 2) % 3, bx = blk / 12;
    int s0 = bx * 4;
    if (tid < 192) {
      int r = tid / 48, c = tid - r * 48;
      const float4* src = (const float4*)(YB + (size_t)(s0 + r) * 768) + kc * 48;
      ((float4*)Xs[r])[c] = src[c];
    }
    __syncthreads();
    int h = hc * 256 + tid;
    const float4* wp = (const float4*)(Wz + (size_t)h * 768) + kc * 48;
    float accA[4] = {};
    float accB[4] = {};
#pragma unroll 6
    for (int k4 = 0; k4 < 24; ++k4) {
      float4 w0 = wp[k4];
      float4 w1 = wp[k4 + 24];
#pragma unroll
      for (int r = 0; r < 4; ++r) {
        float4 x0 = ((const float4*)Xs[r])[k4];
        float4 x1 = ((const float4*)Xs[r])[k4 + 24];
        accA[r] += x0.x * w0.x + x0.y * w0.y + x0.z * w0.z + x0.w * w0.w;
        accB[r] += x1.x * w1.x + x1.y * w1.y + x1.z * w1.z + x1.w * w1.w;
      }
    }
    float bzv = (kc == 0) ? bz[h] : 0.f;
#pragma unroll
    for (int r = 0; r < 4; ++r)
      yp[((size_t)kc * 128 + s0 + r) * 768 + h] = accA[r] + accB[r] + bzv;
  } else if (blk < 768) {
    // ---- zsa half of temp: K-split 4, atomicAdd into out ----
    int idx = blk - 384;
    int kc2 = idx & 3, nc = (idx >> 2) % 3, g = idx / 12;
    if (tid < 192) {
      int r = tid / 48, c = tid - r * 48;
      int row = g * 4 + r;
      int Q = kc2 * 48 + c;
      float4 p0 = *((const float4*)(zsap + (size_t)row * 768) + Q);
      float4 p1 = *((const float4*)(zsap + ((size_t)128 + row) * 768) + Q);
      float4 p2 = *((const float4*)(zsap + ((size_t)256 + row) * 768) + Q);
      float4 p3 = *((const float4*)(zsap + ((size_t)384 + row) * 768) + Q);
      ((float4*)Xs[r])[c] = make_float4(p0.x + p1.x + p2.x + p3.x, p0.y + p1.y + p2.y + p3.y,
                                        p0.z + p1.z + p2.z + p3.z, p0.w + p1.w + p2.w + p3.w);
    }
    __syncthreads();
    int h = nc * 256 + tid;
    float acc[4] = {};
    const float4* wp = (const float4*)(Wh + (size_t)h * 1536 + 768 + kc2 * 192);
#pragma unroll 4
    for (int k4 = 0; k4 < 48; ++k4) {
      float4 wv = wp[k4];
#pragma unroll
      for (int r = 0; r < 4; ++r) {
        float4 xv = ((const float4*)Xs[r])[k4];
        acc[r] += xv.x * wv.x + xv.y * wv.y + xv.z * wv.z + xv.w * wv.w;
      }
    }
#pragma unroll
    for (int r = 0; r < 4; ++r) {
      int row = g * 4 + r;
      int b = row >> 2, s = row & 3;
      if (s < nasp[b]) {
        int orow = row_map[row] + 1;
        atomicAdd(&out[(size_t)orow * 768 + h], acc[r]);
      }
    }
  } else {
    // ---- D @ Wf[:,768:832]^T -> NBR (plain store) ----
    int idx = blk - 768;
    int nc = idx % 3, g = idx / 3;
    if (tid < 64) {
      int r = tid / 16, c = tid - r * 16;
      ((float4*)Xs[r])[c] = *((const float4*)(DG + (size_t)(g * 4 + r) * 64) + c);
    }
    __syncthreads();
    int h = nc * 256 + tid;
    float acc[4] = {};
    const float4* wp = (const float4*)(Wf + (size_t)h * 832 + 768);
#pragma unroll
    for (int k4 = 0; k4 < 16; ++k4) {
      float4 wv = wp[k4];
#pragma unroll
      for (int r = 0; r < 4; ++r) {
        float4 xv = ((const float4*)Xs[r])[k4];
        acc[r] += xv.x * wv.x + xv.y * wv.y + xv.z * wv.z + xv.w * wv.w;
      }
    }
#pragma unroll
    for (int r = 0; r < 4; ++r)
      NBR[(size_t)(g * 4 + r) * 768 + h] = acc[r];
  }
}

// ---------------- KD (stage 4): NBR += y @ Wf[:, :768]^T (K-split 4, atomic) ----------------
__global__ __launch_bounds__(256) void kD(
    const float* __restrict__ yp, const float* __restrict__ Wf,
    float* __restrict__ NBR) {
  int blk = blockIdx.x, tid = threadIdx.x;
  int kc = blk & 3, nc = (blk >> 2) % 3, g = blk / 12;
  __shared__ float Xs[4][192];
  if (tid < 192) {
    int r = tid / 48, c = tid - r * 48;
    int row = g * 4 + r;
    int Q = kc * 48 + c;
    float4 p0 = *((const float4*)(yp + (size_t)row * 768) + Q);
    float4 p1 = *((const float4*)(yp + ((size_t)128 + row) * 768) + Q);
    float4 p2 = *((const float4*)(yp + ((size_t)256 + row) * 768) + Q);
    float4 p3 = *((const float4*)(yp + ((size_t)384 + row) * 768) + Q);
    ((float4*)Xs[r])[c] = make_float4(p0.x + p1.x + p2.x + p3.x, p0.y + p1.y + p2.y + p3.y,
                                      p0.z + p1.z + p2.z + p3.z, p0.w + p1.w + p2.w + p3.w);
  }
  __syncthreads();
  int h = nc * 256 + tid;
  float acc[4] = {};
  const float4* wp = (const float4*)(Wf + (size_t)h * 832 + kc * 192);
#pragma unroll 4
  for (int k4 = 0; k4 < 48; ++k4) {
    float4 wv = wp[k4];
#pragma unroll
    for (int r = 0; r < 4; ++r) {
      float4 xv = ((const float4*)Xs[r])[k4];
      acc[r] += xv.x * wv.x + xv.y * wv.y + xv.z * wv.z + xv.w * wv.w;
    }
  }
#pragma unroll
  for (int r = 0; r < 4; ++r)
    atomicAdd(&NBR[(size_t)(g * 4 + r) * 768 + h], acc[r]);
}

// ---------------- KE (stage 5): out += NBR @ Wh[:, :768]^T (K-split 4, atomic) ----------------
__global__ __launch_bounds__(256) void kE(
    const float* __restrict__ NBR, const float* __restrict__ Wh,
    const int* __restrict__ row_map, const int* __restrict__ nasp,
    float* __restrict__ out) {
  int blk = blockIdx.x, tid = threadIdx.x;
  int kc = blk & 3, nc = (blk >> 2) % 3, g = blk / 12;
  __shared__ float Xs[4][192];
  if (tid < 192) {
    int r = tid / 48, c = tid - r * 48;
    ((float4*)Xs[r])[c] = *((const float4*)(NBR + (size_t)(g * 4 + r) * 768 + kc * 192) + c);
  }
  __syncthreads();
  int h = nc * 256 + tid;
  float acc[4] = {};
  const float4* wp = (const float4*)(Wh + (size_t)h * 1536 + kc * 192);
#pragma unroll 4
  for (int k4 = 0; k4 < 48; ++k4) {
    float4 wv = wp[k4];
#pragma unroll
    for (int r = 0; r < 4; ++r) {
      float4 xv = ((const float4*)Xs[r])[k4];
      acc[r] += xv.x * wv.x + xv.y * wv.y + xv.z * wv.z + xv.w * wv.w;
    }
  }
#pragma unroll
  for (int r = 0; r < 4; ++r) {
    int row = g * 4 + r;
    int b = row >> 2, s = row & 3;
    if (s < nasp[b]) {
      int orow = row_map[row] + 1;
      atomicAdd(&out[(size_t)orow * 768 + h], acc[r]);
    }
  }
}

extern "C" void kernel_launch(void* const* d_in, const int* in_sizes, int n_in,
                              void* d_out, int out_size, void* d_ws, size_t ws_size,
                              hipStream_t stream) {
  const float* bert = (const float*)d_in[0];
  const float* dep  = (const float*)d_in[1];
  const int*   adj  = (const int*)d_in[2];
  const int*   asps = (const int*)d_in[3];
  const int*   aspe = (const int*)d_in[4];
  const float* Wz   = (const float*)d_in[5];
  const float* bz   = (const float*)d_in[6];
  const float* wa   = (const float*)d_in[7];
  const float* ba   = (const float*)d_in[8];
  const float* Wf   = (const float*)d_in[9];
  const float* Wh   = (const float*)d_in[10];
  float* out = (float*)d_out;
  char* ws = (char*)d_ws;

  int*   aspect_slot = (int*)(ws + OFF_ASLOT);
  int*   aspect_idx  = (int*)(ws + OFF_AIDX);
  int*   nasp        = (int*)(ws + OFF_NASP);
  int*   aj_cnt      = (int*)(ws + OFF_AJCNT);
  int*   aj_idx      = (int*)(ws + OFF_AJIDX);
  int*   row_map     = (int*)(ws + OFF_RMAP);
  float* bzd         = (float*)(ws + OFF_BZD);
  float* YB          = (float*)(ws + OFF_YB);
  float* DG          = (float*)(ws + OFF_DG);
  float* yp          = (float*)(ws + OFF_YP);
  float* zsap        = (float*)(ws + OFF_ZSAP);
  float* NBR         = (float*)(ws + OFF_NBR);
  float* viP         = (float*)(ws + OFF_VIP);
  float* vjP         = (float*)(ws + OFF_VJP);

  kA<<<4153, 256, 0, stream>>>(adj, asps, aspe, Wz, wa, bz, bert,
                               aspect_slot, aspect_idx, nasp, aj_cnt, aj_idx, row_map,
                               viP, vjP, bzd, out);
  kB<<<416, 256, 0, stream>>>(dep, bert, wa, ba, viP, vjP, bzd, Wz, bz,
                              nasp, aspect_idx, aj_cnt, aj_idx, row_map,
                              YB, DG, zsap);
  kC<<<864, 256, 0, stream>>>(YB, DG, zsap, Wz, bz, Wf, Wh, row_map, nasp, yp, NBR, out);
  kD<<<384, 256, 0, stream>>>(yp, Wf, NBR);
  kE<<<384, 256, 0, stream>>>(NBR, Wh, row_map, nasp, out);
}